// Round 4
// baseline (110.223 us; speedup 1.0000x reference)
//
#include <hip/hip_runtime.h>
#include <hip/hip_bf16.h>

// out = (Q K^T * SCALE) @ V  ==  Q @ (SCALE * K^T V)   (softmax discarded in ref)
// B=32, T=2048, E=1024, H=64.  M = B*T = 65536.
// Chain: k_wt (W transpose->bf16), k_qkv (QKV proj + fused per-block K^T V
// partials), k_red (reduce partials -> KtV^T bf16), k_out (Q @ KtV).

using bf16x8 = __attribute__((ext_vector_type(8))) short;
using f32x4  = __attribute__((ext_vector_type(4))) float;
using u32x4  = __attribute__((ext_vector_type(4))) unsigned int;
using u32x2  = __attribute__((ext_vector_type(2))) unsigned int;
using u16    = unsigned short;

__device__ __forceinline__ u16 f2bf(float f) {
    unsigned u = __builtin_bit_cast(unsigned, f);
    u += 0x7fffu + ((u >> 16) & 1u);          // RNE
    return (u16)(u >> 16);
}

#define G2L16(g, l) __builtin_amdgcn_global_load_lds(                         \
    (const __attribute__((address_space(1))) void*)(g),                       \
    (__attribute__((address_space(3))) void*)(l), 16, 0, 0)

// ---------------- k_wt: WT[n][e] = W*[e][n] as bf16 (LDS transpose) ----------------
__global__ __launch_bounds__(256) void k_wt(const float* __restrict__ Wq,
                                            const float* __restrict__ Wk,
                                            const float* __restrict__ Wv,
                                            u16* __restrict__ WT) {
    __shared__ float Wl[64][68];
    const int seg = blockIdx.x >> 4, chunk = blockIdx.x & 15;   // 48 blocks
    const float* W = (seg == 0) ? Wq : (seg == 1) ? Wk : Wv;
    const int e0 = chunk * 64;
    const int tid = threadIdx.x;
    const int lr = tid >> 4, lc = (tid & 15) * 4;
#pragma unroll
    for (int p = 0; p < 4; ++p)
        *(f32x4*)&Wl[lr + p * 16][lc] = *(const f32x4*)(W + (size_t)(e0 + lr + p * 16) * 64 + lc);
    __syncthreads();
    const int c = tid >> 2, eb = (tid & 3) * 16;
    u32x4 o0, o1;
#pragma unroll
    for (int q = 0; q < 4; ++q)
        o0[q] = (unsigned)f2bf(Wl[eb + 2 * q][c]) | ((unsigned)f2bf(Wl[eb + 2 * q + 1][c]) << 16);
#pragma unroll
    for (int q = 0; q < 4; ++q)
        o1[q] = (unsigned)f2bf(Wl[eb + 8 + 2 * q][c]) | ((unsigned)f2bf(Wl[eb + 9 + 2 * q][c]) << 16);
    u16* dst = WT + (size_t)(seg * 64 + c) * 1024 + e0 + eb;
    *(u32x4*)dst = o0;
    *(u32x4*)(dst + 8) = o1;
}

// ---------------- k_qkv: Q = x@Wq+bq (bf16 out) + fused partial K^T V ----------------
// 512 thr (8 waves), M-tile 64, N=192, BK=64, 16 chunks in 4 macros of 256 cols.
// x: REG-staged in 1-KB row bursts -> bf16 LDS [64][256] dbuf (2*32 KB), swz ^((r&7)<<4).
// WT: G2L16 per chunk [192][64] dbuf (2*24 KB), source pre-swizzled.  LDS 112 KB.
// vmcnt ledger (issue order per iter: WT3(ch+1) then x8@c==0):
//   c<=1 && mk<3 -> 11 (WT3+x8 newer);  else -> 3;  ch==15 -> 0.
__global__ __launch_bounds__(512, 2) void k_qkv(const float* __restrict__ x,
                                                const u16* __restrict__ WT,
                                                const float* __restrict__ bq,
                                                const float* __restrict__ bk,
                                                const float* __restrict__ bv,
                                                u16* __restrict__ Qb,
                                                float* __restrict__ part) {
    __shared__ __align__(16) char lds[114688];    // x: 2*32768 @0, WT: 2*24576 @65536
    const int tid  = threadIdx.x;
    const int wave = tid >> 6, lane = tid & 63;
    const int wr = wave >> 2, wc = wave & 3;      // 2M x 4N wave grid
    const size_t row0 = (size_t)blockIdx.x * 64;

    // x reg-staging geometry: thread covers row xrow, 16-B slots {q*8+xcs} of a 1-KB span
    const int xrow = tid >> 3;                    // 0..63
    const int xcs  = tid & 7;                     // 0..7
    const float* const xrowp = x + (row0 + xrow) * 1024 + xcs * 4;

    // WT staging (pre-swizzled source, linear LDS dest)
    size_t wsrc[3]; int wdstl[3];
#pragma unroll
    for (int j = 0; j < 3; ++j) {
        const int n  = (tid >> 3) + j * 64;
        const int cb = ((tid & 7) * 16) ^ ((n & 7) << 4);
        wsrc[j] = (size_t)n * 1024 + (cb >> 1);
        wdstl[j] = j * 8192 + wave * 1024;
    }

    f32x4 acc[2][3];
#pragma unroll
    for (int m = 0; m < 2; ++m)
#pragma unroll
        for (int n = 0; n < 3; ++n)
#pragma unroll
            for (int r = 0; r < 4; ++r) acc[m][n][r] = 0.0f;

    f32x4 xreg[8];

    // ---- prologue: fetch x macro 0, WT chunk 0; write x -> buf0 ----
#pragma unroll
    for (int q = 0; q < 8; ++q) xreg[q] = *(const f32x4*)(xrowp + q * 32);
    asm volatile("" ::: "memory");
    __builtin_amdgcn_sched_barrier(0);
#pragma unroll
    for (int j = 0; j < 3; ++j) G2L16(WT + wsrc[j], lds + 65536 + wdstl[j]);
    {
        char* const xb = lds;                     // buf0
#pragma unroll
        for (int q = 0; q < 8; ++q) {
            u32x2 pk;
            pk[0] = (unsigned)f2bf(xreg[q][0]) | ((unsigned)f2bf(xreg[q][1]) << 16);
            pk[1] = (unsigned)f2bf(xreg[q][2]) | ((unsigned)f2bf(xreg[q][3]) << 16);
            *(u32x2*)(xb + ((xrow * 512 + q * 64 + xcs * 8) ^ ((xrow & 7) << 4))) = pk;
        }
    }
    asm volatile("s_waitcnt lgkmcnt(0)" ::: "memory");
    __builtin_amdgcn_s_barrier();

    // ---- main loop: 4 macros x 4 chunks ----
#pragma unroll
    for (int mk = 0; mk < 4; ++mk) {
#pragma unroll
        for (int c = 0; c < 4; ++c) {
            const int ch = mk * 4 + c;
            // (a) stage WT for ch+1
            if (ch < 15) {
                char* const wbase = lds + 65536 + ((ch + 1) & 1) * 24576;
                const int k0 = (ch + 1) * 64;
#pragma unroll
                for (int j = 0; j < 3; ++j) G2L16(WT + wsrc[j] + k0, wbase + wdstl[j]);
            }
            // (b) issue x loads for next macro
            if (c == 0 && mk < 3) {
#pragma unroll
                for (int q = 0; q < 8; ++q)
                    xreg[q] = *(const f32x4*)(xrowp + (mk + 1) * 256 + q * 32);
                asm volatile("" ::: "memory");
                __builtin_amdgcn_sched_barrier(0);
            }
            // (c) wait WT(ch) landed (never drains deep prefetch mid-loop)
            if (c <= 1 && mk < 3)  asm volatile("s_waitcnt vmcnt(11)" ::: "memory");
            else if (ch < 15)      asm volatile("s_waitcnt vmcnt(3)" ::: "memory");
            else                   asm volatile("s_waitcnt vmcnt(0)" ::: "memory");
            __builtin_amdgcn_s_barrier();
            __builtin_amdgcn_sched_barrier(0);

            // (d) compute chunk c of macro mk
            {
                const char* const xb = lds + (mk & 1) * 32768;
                const char* const wb = lds + 65536 + (ch & 1) * 24576;
#pragma unroll
                for (int ks = 0; ks < 2; ++ks) {
                    bf16x8 af[2];
#pragma unroll
                    for (int m = 0; m < 2; ++m) {
                        const int r = wr * 32 + m * 16 + (lane & 15);
                        const int P = (r * 512 + c * 128 + ks * 64 + (lane >> 4) * 16) ^ ((r & 7) << 4);
                        af[m] = *(const bf16x8*)(xb + P);
                    }
#pragma unroll
                    for (int n = 0; n < 3; ++n) {
                        const int nn = wc * 48 + n * 16 + (lane & 15);
                        const int P  = (nn * 128 + ks * 64 + (lane >> 4) * 16) ^ ((nn & 7) << 4);
                        const bf16x8 bfr = *(const bf16x8*)(wb + P);
                        acc[0][n] = __builtin_amdgcn_mfma_f32_16x16x32_bf16(af[0], bfr, acc[0][n], 0, 0, 0);
                        acc[1][n] = __builtin_amdgcn_mfma_f32_16x16x32_bf16(af[1], bfr, acc[1][n], 0, 0, 0);
                    }
                }
            }
            // (e) convert + write next x macro into the other buffer
            if (c == 3 && mk < 3) {
                char* const xb = lds + ((mk + 1) & 1) * 32768;
#pragma unroll
                for (int q = 0; q < 8; ++q) {
                    u32x2 pk;
                    pk[0] = (unsigned)f2bf(xreg[q][0]) | ((unsigned)f2bf(xreg[q][1]) << 16);
                    pk[1] = (unsigned)f2bf(xreg[q][2]) | ((unsigned)f2bf(xreg[q][3]) << 16);
                    *(u32x2*)(xb + ((xrow * 512 + q * 64 + xcs * 8) ^ ((xrow & 7) << 4))) = pk;
                }
                asm volatile("s_waitcnt lgkmcnt(0)" ::: "memory");
            }
            __builtin_amdgcn_sched_barrier(0);
            __builtin_amdgcn_s_barrier();
        }
    }

    // ---- epilogue: Q -> global; K,V -> LDS transposed bf16 tiles (+bias) ----
    // D-layout: col = lane&15, row = (lane>>4)*4 + rr
    u16* const Kt = (u16*)lds;                    // [64][72]  (h_k major)
    u16* const Vt = (u16*)(lds + 16384);          // [64][72]  (h_v major)
#pragma unroll
    for (int n = 0; n < 3; ++n) {
        const int ncol = wc * 48 + n * 16;
        const int seg = ncol >> 6;
        const int col = (ncol & 63) + (lane & 15);
        const float bias = ((seg == 0) ? bq : (seg == 1) ? bk : bv)[col];
#pragma unroll
        for (int m = 0; m < 2; ++m) {
            const int rloc = wr * 32 + m * 16 + ((lane >> 4) << 2);
            if (seg == 0) {
#pragma unroll
                for (int rr = 0; rr < 4; ++rr)
                    Qb[(row0 + rloc + rr) * 64 + col] = f2bf(acc[m][n][rr] + bias);
            } else {
                u16* const T = (seg == 1) ? Kt : Vt;
#pragma unroll
                for (int rr = 0; rr < 4; ++rr)
                    T[col * 72 + rloc + rr] = f2bf(acc[m][n][rr] + bias);
            }
        }
    }
    __syncthreads();

    // ---- fused K^T V partial: D[hv][hk] = sum_rows V[row][hv] * K[row][hk] ----
    float* const P = part + (size_t)blockIdx.x * 4096;
#pragma unroll
    for (int i = 0; i < 2; ++i) {
        const int f = wave * 2 + i;
        const int m0 = (f & 3) * 16;              // h_v
        const int n0 = (f >> 2) * 16;             // h_k
        f32x4 d;
        d[0] = d[1] = d[2] = d[3] = 0.0f;
#pragma unroll
        for (int ks = 0; ks < 2; ++ks) {
            const bf16x8 a = *(const bf16x8*)(Vt + (m0 + (lane & 15)) * 72 + ks * 32 + (lane >> 4) * 8);
            const bf16x8 b = *(const bf16x8*)(Kt + (n0 + (lane & 15)) * 72 + ks * 32 + (lane >> 4) * 8);
            d = __builtin_amdgcn_mfma_f32_16x16x32_bf16(a, b, d, 0, 0, 0);
        }
#pragma unroll
        for (int rr = 0; rr < 4; ++rr)
            P[(m0 + (lane >> 4) * 4 + rr) * 64 + n0 + (lane & 15)] = d[rr];
    }
}

// ---------------- k_red: KtVT[b][o] = SCALE * sum_c part[b*32+c][o], bf16 ----------------
__global__ __launch_bounds__(256) void k_red(const float* __restrict__ part,
                                             u16* __restrict__ KtVT) {
    const int b = blockIdx.x >> 2;
    const int o0 = (blockIdx.x & 3) * 1024 + threadIdx.x * 4;
    const float* const Pb = part + (size_t)b * 32 * 4096;
    f32x4 s;
    s[0] = s[1] = s[2] = s[3] = 0.0f;
#pragma unroll 8
    for (int c = 0; c < 32; ++c) s += *(const f32x4*)(Pb + c * 4096 + o0);
    s *= 0.125f;                                   // SCALE = 64^-0.5
    u32x2 pk;
    pk[0] = (unsigned)f2bf(s[0]) | ((unsigned)f2bf(s[1]) << 16);
    pk[1] = (unsigned)f2bf(s[2]) | ((unsigned)f2bf(s[3]) << 16);
    *(u32x2*)(KtVT + (size_t)b * 4096 + o0) = pk;
}

// ---------------- k_out: out = Q @ KtV (K=64), fp32 out ----------------
__global__ __launch_bounds__(256) void k_out(const u16* __restrict__ Qb,
                                             const u16* __restrict__ KtVT,
                                             float* __restrict__ out) {
    const int tid = threadIdx.x;
    const int wave = tid >> 6, lane = tid & 63;
    const size_t m0 = (size_t)blockIdx.x * 64 + wave * 16;
    const int b = blockIdx.x >> 5;            // 32 blocks per batch
    const u16* const Bp = KtVT + (size_t)b * 4096;

    bf16x8 bfrag[2][4];
#pragma unroll
    for (int ks = 0; ks < 2; ++ks)
#pragma unroll
        for (int nt = 0; nt < 4; ++nt)
            bfrag[ks][nt] = *(const bf16x8*)(Bp + (nt * 16 + (lane & 15)) * 64 + ks * 32 + (lane >> 4) * 8);

    f32x4 acc[4];
#pragma unroll
    for (int nt = 0; nt < 4; ++nt)
#pragma unroll
        for (int r = 0; r < 4; ++r) acc[nt][r] = 0.0f;

#pragma unroll
    for (int ks = 0; ks < 2; ++ks) {
        const bf16x8 a = *(const bf16x8*)(Qb + (m0 + (lane & 15)) * 64 + ks * 32 + (lane >> 4) * 8);
#pragma unroll
        for (int nt = 0; nt < 4; ++nt)
            acc[nt] = __builtin_amdgcn_mfma_f32_16x16x32_bf16(a, bfrag[ks][nt], acc[nt], 0, 0, 0);
    }
#pragma unroll
    for (int nt = 0; nt < 4; ++nt)
#pragma unroll
        for (int rr = 0; rr < 4; ++rr)
            out[(m0 + (lane >> 4) * 4 + rr) * 64 + nt * 16 + (lane & 15)] = acc[nt][rr];
}

extern "C" void kernel_launch(void* const* d_in, const int* in_sizes, int n_in,
                              void* d_out, int out_size, void* d_ws, size_t ws_size,
                              hipStream_t stream) {
    (void)in_sizes; (void)n_in; (void)out_size; (void)ws_size;
    const float* x  = (const float*)d_in[0];
    const float* Wq = (const float*)d_in[1];
    const float* bq = (const float*)d_in[2];
    const float* Wk = (const float*)d_in[3];
    const float* bk = (const float*)d_in[4];
    const float* Wv = (const float*)d_in[5];
    const float* bv = (const float*)d_in[6];
    float* out = (float*)d_out;

    char* ws = (char*)d_ws;                       // layout (~25 MB total):
    u16*  WT   = (u16*)(ws);                      // 0x0000000: 384 KB  WT bf16 [192][1024]
    u16*  Qb   = (u16*)(ws + 0x60000);            // 0x0060000: 8 MB    Q bf16 [65536][64]
    float* part= (float*)(ws + 0x860000);         // 0x0860000: 16 MB   partials [1024][64][64] f32
    u16*  KtVT = (u16*)(ws + 0x1860000);          // 0x1860000: 256 KB  KtV^T bf16 [32][64][64]

    k_wt <<<48,   256, 0, stream>>>(Wq, Wk, Wv, WT);
    k_qkv<<<1024, 512, 0, stream>>>(x, WT, bq, bk, bv, Qb, part);
    k_red<<<128,  256, 0, stream>>>(part, KtVT);
    k_out<<<1024, 256, 0, stream>>>(Qb, KtVT, out);
}